// Round 2
// baseline (1768.796 us; speedup 1.0000x reference)
//
#include <hip/hip_runtime.h>
#include <hip/hip_fp16.h>

// ---------------------------------------------------------------------------
// Bidirectional 5-layer LSTM decoder, B=1024, H=32, T=200, feedback y->x.
// All reference tensors are float32 (jnp.float32) -> read fp32, write fp32.
// One wave per batch row: lane = d*32+u. Cross-unit traffic via per-wave LDS.
// Weights repacked once per call into f16 layout WT[l][d][k2][u][g][2] so the
// inner loop is one dwordx4 = 4 gates x 2 k-steps per lane, consumed by
// v_dot2_f32_f16 (2 MACs/inst, fp32 accumulate). Cell state c,h kept fp32.
// ---------------------------------------------------------------------------

#define T_STEPS 200
#define BATCH 1024

// ws byte layout (f16 weights = same byte size as round-1 bf16)
#define W_ELEMS     107520            // f16 packed weights
#define BIAS_OFF_B  215040            // 1280 floats [l][d][u][g]
#define WLIN_OFF_B  220160            // 192 floats [3][64]
#define BLIN_OFF_B  220928            // 3 floats
#define START_OFF_B 220940            // 3 floats

typedef _Float16 h2 __attribute__((ext_vector_type(2)));

__global__ __launch_bounds__(256) void prep_kernel(
    const float* __restrict__ Wih0, const float* __restrict__ Whh0,
    const float* __restrict__ bih0, const float* __restrict__ bhh0,
    const float* __restrict__ Wih,  const float* __restrict__ Whh,
    const float* __restrict__ bih,  const float* __restrict__ bhh,
    const float* __restrict__ Wlin, const float* __restrict__ blin,
    const float* __restrict__ stok, char* __restrict__ ws)
{
    int i = blockIdx.x * 256 + threadIdx.x;
    _Float16* Wo = (_Float16*)ws;
    float* biasf  = (float*)(ws + BIAS_OFF_B);
    float* wlinf  = (float*)(ws + WLIN_OFF_B);
    float* blinf  = (float*)(ws + BLIN_OFF_B);
    float* startf = (float*)(ws + START_OFF_B);

    if (i < W_ELEMS) {
        int l, d, r, Kx;
        if (i < 9216) { l = 0; d = i / 4608; r = i % 4608; Kx = 4; }  // K0 = 4(pad) + 32
        else {
            int e = i - 9216;
            l = 1 + e / 24576;
            int r2 = e % 24576;
            d = r2 / 12288; r = r2 % 12288; Kx = 64;                   // K = 64 + 32
        }
        int k2 = r >> 8;            // 256 elems per k-pair block (32u * 4g * 2)
        int q  = r & 255;
        int u  = q >> 3;
        int g  = (q >> 1) & 3;
        int p  = q & 1;
        int k  = k2 * 2 + p;
        int gr = g * 32 + u;        // gate row in 4H (torch order i,f,g,o)
        float v = 0.f;
        if (k < Kx) {
            if (l == 0) { if (k < 3) v = Wih0[(d * 128 + gr) * 3 + k]; }
            else        v = Wih[(((l - 1) * 2 + d) * 128 + gr) * 64 + k];
        } else {
            int kh = k - Kx;
            if (l == 0) v = Whh0[(d * 128 + gr) * 32 + kh];
            else        v = Whh[(((l - 1) * 2 + d) * 128 + gr) * 32 + kh];
        }
        Wo[i] = (_Float16)v;
    } else if (i < W_ELEMS + 1280) {
        int b = i - W_ELEMS;                 // [l*2+d][u*4+g]
        int ld = b / 128; int rem = b % 128;
        int u = rem / 4;  int g = rem % 4;
        int gr = g * 32 + u;
        float v;
        if (ld < 2) v = bih0[ld * 128 + gr] + bhh0[ld * 128 + gr];
        else        v = bih[(ld - 2) * 128 + gr] + bhh[(ld - 2) * 128 + gr];
        biasf[b] = v;
    } else if (i < W_ELEMS + 1280 + 192) {
        wlinf[i - (W_ELEMS + 1280)] = Wlin[i - (W_ELEMS + 1280)];
    } else if (i < W_ELEMS + 1280 + 192 + 3) {
        blinf[i - (W_ELEMS + 1280 + 192)] = blin[i - (W_ELEMS + 1280 + 192)];
    } else if (i < W_ELEMS + 1280 + 192 + 6) {
        startf[i - (W_ELEMS + 1280 + 192 + 3)] = stok[i - (W_ELEMS + 1280 + 192 + 3)];
    }
}

__device__ __forceinline__ float sigm(float x)  { return 1.f / (1.f + __expf(-x)); }
__device__ __forceinline__ float tanhx(float x) { return 2.f * sigm(2.f * x) - 1.f; }
__device__ __forceinline__ h2 as_h2(unsigned v) { return __builtin_bit_cast(h2, v); }

__device__ __forceinline__ float fdot2f(h2 a, h2 b, float c) {
#if __has_builtin(__builtin_amdgcn_fdot2)
    return __builtin_amdgcn_fdot2(a, b, c, false);
#else
    return fmaf((float)a.x, (float)b.x, fmaf((float)a.y, (float)b.y, c));
#endif
}

#define DOT4(WV, XV)                                  \
    acc.x = fdot2f(as_h2((WV).x), (XV), acc.x);       \
    acc.y = fdot2f(as_h2((WV).y), (XV), acc.y);       \
    acc.z = fdot2f(as_h2((WV).z), (XV), acc.z);       \
    acc.w = fdot2f(as_h2((WV).w), (XV), acc.w);

__device__ __forceinline__ unsigned short f2h_bits(float x) {
    return __builtin_bit_cast(unsigned short, (_Float16)x);
}

__global__ __launch_bounds__(256) void lstm_kernel(
    const char* __restrict__ ws,
    const float* __restrict__ h0,
    const float* __restrict__ c0,
    float* __restrict__ out)
{
    const int tid  = threadIdx.x;
    const int w    = tid >> 6;          // wave in block (0..3) = row slot
    const int lane = tid & 63;
    const int d    = lane >> 5;
    const int u    = lane & 31;
    const int row  = blockIdx.x * 4 + w;

    // f16 activation buffers, uint-declared for 4B alignment. All traffic is
    // intra-wave; __syncthreads() per layer both orders LDS and convoys the
    // 4 waves so their weight sweeps share L1 lines.
    __shared__ unsigned int xbhU[4][32];   // layer input (64 f16)
    __shared__ unsigned int hbhU[4][32];   // recurrent h (64 f16)

    const _Float16* W = (const _Float16*)ws;
    const float* biasf  = (const float*)(ws + BIAS_OFF_B);
    const float* wlinf  = (const float*)(ws + WLIN_OFF_B);
    const float* blinf  = (const float*)(ws + BLIN_OFF_B);
    const float* startf = (const float*)(ws + START_OFF_B);

    float hs[5], cs[5];
#pragma unroll
    for (int l = 0; l < 5; l++) {
        int idx = ((2 * l + d) * BATCH + row) * 32 + u;
        hs[l] = h0[idx];
        cs[l] = c0[idx];
    }
    float4 bias4[5];
#pragma unroll
    for (int l = 0; l < 5; l++)
        bias4[l] = *(const float4*)(biasf + ((l * 2 + d) * 32 + u) * 4);

    // per-(l,d) weight base as uint4 (= 8 f16 = 4 gates x 2 k) + lane offset u
    const uint4* wp0 = (const uint4*)W + d * 576 + u;                 // layer 0
    const uint4* wpl[4];
#pragma unroll
    for (int l = 1; l < 5; l++)
        wpl[l - 1] = (const uint4*)W + 1152 + ((l - 1) * 2 + d) * 1536 + u;

    const float wl0 = wlinf[lane], wl1 = wlinf[64 + lane], wl2 = wlinf[128 + lane];
    const float bl0 = blinf[0], bl1 = blinf[1], bl2 = blinf[2];
    float y0 = startf[0], y1 = startf[1], y2 = startf[2];

    for (int t = 0; t < T_STEPS; t++) {
        // ----- layer 0 -----
        ((unsigned short*)hbhU[w])[lane] = f2h_bits(hs[0]);
        __syncthreads();
        {
            float4 acc = bias4[0];
            h2 y01; y01.x = (_Float16)y0; y01.y = (_Float16)y1;
            h2 y2p; y2p.x = (_Float16)y2; y2p.y = (_Float16)0.f;
            uint4 wv = wp0[0];
            DOT4(wv, y01);
            wv = wp0[32];
            DOT4(wv, y2p);
            const unsigned int* hp = hbhU[w] + d * 16;
#pragma unroll
            for (int k2 = 0; k2 < 16; k2++) {
                uint4 w2 = wp0[(2 + k2) * 32];
                h2 hx = as_h2(hp[k2]);
                DOT4(w2, hx);
            }
            float ii = sigm(acc.x), ff = sigm(acc.y), gg = tanhx(acc.z), oo = sigm(acc.w);
            cs[0] = ff * cs[0] + ii * gg;
            hs[0] = oo * tanhx(cs[0]);
        }

        // ----- layers 1..4 -----
#pragma unroll
        for (int l = 1; l < 5; l++) {
            ((unsigned short*)xbhU[w])[lane] = f2h_bits(hs[l - 1]);
            ((unsigned short*)hbhU[w])[lane] = f2h_bits(hs[l]);
            __syncthreads();
            float4 acc = bias4[l];
            const uint4* wp = wpl[l - 1];
            const unsigned int* xp = xbhU[w];
#pragma unroll 8
            for (int k2 = 0; k2 < 32; k2++) {
                uint4 wv = wp[k2 * 32];
                h2 xv = as_h2(xp[k2]);
                DOT4(wv, xv);
            }
            const unsigned int* hp = hbhU[w] + d * 16;
#pragma unroll 8
            for (int k2 = 0; k2 < 16; k2++) {
                uint4 wv = wp[(32 + k2) * 32];
                h2 hx = as_h2(hp[k2]);
                DOT4(wv, hx);
            }
            float ii = sigm(acc.x), ff = sigm(acc.y), gg = tanhx(acc.z), oo = sigm(acc.w);
            cs[l] = ff * cs[l] + ii * gg;
            hs[l] = oo * tanhx(cs[l]);
        }

        // ----- output linear + tanh + feedback (concat = hs[4] per lane) -----
        {
            float v = hs[4];
            float p0 = v * wl0, p1 = v * wl1, p2 = v * wl2;
#pragma unroll
            for (int off = 32; off >= 1; off >>= 1) {
                p0 += __shfl_xor(p0, off);
                p1 += __shfl_xor(p1, off);
                p2 += __shfl_xor(p2, off);
            }
            y0 = tanhx(p0 + bl0);
            y1 = tanhx(p1 + bl1);
            y2 = tanhx(p2 + bl2);
            if (lane < 3) {
                float yv = (lane == 0) ? y0 : (lane == 1 ? y1 : y2);
                out[(t * BATCH + row) * 3 + lane] = yv;
            }
        }
    }
}

extern "C" void kernel_launch(void* const* d_in, const int* in_sizes, int n_in,
                              void* d_out, int out_size, void* d_ws, size_t ws_size,
                              hipStream_t stream)
{
    const float* h0   = (const float*)d_in[0];
    const float* c0   = (const float*)d_in[1];
    const float* stok = (const float*)d_in[2];
    const float* Wih0 = (const float*)d_in[3];
    const float* Whh0 = (const float*)d_in[4];
    const float* bih0 = (const float*)d_in[5];
    const float* bhh0 = (const float*)d_in[6];
    const float* Wih  = (const float*)d_in[7];
    const float* Whh  = (const float*)d_in[8];
    const float* bih  = (const float*)d_in[9];
    const float* bhh  = (const float*)d_in[10];
    const float* Wlin = (const float*)d_in[11];
    const float* blin = (const float*)d_in[12];

    prep_kernel<<<426, 256, 0, stream>>>(Wih0, Whh0, bih0, bhh0, Wih, Whh,
                                         bih, bhh, Wlin, blin, stok, (char*)d_ws);
    lstm_kernel<<<256, 256, 0, stream>>>((const char*)d_ws, h0, c0,
                                         (float*)d_out);
}